// Round 1
// baseline (92.548 us; speedup 1.0000x reference)
//
#include <hip/hip_runtime.h>
#include <math.h>

// Problem constants (reference: N=8, MA=24, DESIGN=26, RADIAL=15, SOFTENING=3, RM=5.0)
constexpr int MAC = 24;            // atoms per molecule
constexpr int DES = 26;            // sphere design points
constexpr int RAD = 15;            // radial points
constexpr int MS  = RAD * DES;     // 390 samples per atom
constexpr int MX  = MAC * MS;      // 9360 grid points per molecule
constexpr int NCHUNK = (MX + 255) / 256;  // 37 blocks of 256 per molecule

__global__ __launch_bounds__(256) void becke_grid_kernel(
    const float* __restrict__ coords,   // [N, MAC, 3]
    const float* __restrict__ sphere,   // [DES, 3]
    const float* __restrict__ sw,       // [DES]
    float* __restrict__ out_grid,       // [N, MX, 3]
    float* __restrict__ out_dv,         // [N, MX, MAC, 3]
    float* __restrict__ out_w)          // [N, MX]
{
    __shared__ float cs[MAC * 3];            // molecule coords
    __shared__ float inv_dm[MAC][MAC];       // 1 / clip(dm, 1e-12)
    __shared__ float sph[DES * 3];
    __shared__ float sws[DES];
    __shared__ float rr[RAD];
    __shared__ float ww[RAD];
    __shared__ float rxs[256][MAC + 1];      // +1 pad: stride 25 -> conflict-free

    const int tid   = threadIdx.x;
    const int n     = blockIdx.x / NCHUNK;
    const int chunk = blockIdx.x - n * NCHUNK;

    // ---- cooperative staging ----
    for (int e = tid; e < MAC * 3; e += 256) cs[e] = coords[n * MAC * 3 + e];
    for (int e = tid; e < DES * 3; e += 256) sph[e] = sphere[e];
    if (tid < DES) sws[tid] = sw[tid];
    if (tid < RAD) {
        // Gauss-Chebyshev + Becke transform radial quadrature, f64 for safety
        double i   = (double)tid + 1.0;
        double z   = -cos(M_PI * (2.0 * i - 1.0) / (2.0 * (double)RAD));
        double omz = 1.0 - z;
        double dr  = 2.0 * 5.0 / (omz * omz);       // RM = 5.0
        double r   = 5.0 * (1.0 + z) / omz;
        double w1  = sqrt(1.0 - z * z) * dr * M_PI / (double)RAD;
        double w   = r * r * 4.0 * M_PI * w1;
        rr[tid] = (float)r;
        ww[tid] = (float)w;
    }
    __syncthreads();
    for (int e = tid; e < MAC * MAC; e += 256) {
        int i = e / MAC, j = e - (e / MAC) * MAC;
        float dx = cs[i * 3 + 0] - cs[j * 3 + 0];
        float dy = cs[i * 3 + 1] - cs[j * 3 + 1];
        float dz = cs[i * 3 + 2] - cs[j * 3 + 2];
        float dd = sqrtf(dx * dx + dy * dy + dz * dz);
        inv_dm[i][j] = 1.0f / fmaxf(dd, 1e-12f);
    }
    __syncthreads();

    const int s = chunk * 256 + tid;
    if (s >= MX) return;

    const int a = s / MS;             // parent atom
    const int t = s - a * MS;
    const int k = t / DES;            // radial index
    const int d = t - k * DES;        // design index

    const float r  = rr[k];
    const float gx = cs[a * 3 + 0] + r * sph[d * 3 + 0];
    const float gy = cs[a * 3 + 1] + r * sph[d * 3 + 1];
    const float gz = cs[a * 3 + 2] + r * sph[d * 3 + 2];

    {
        size_t gb = ((size_t)n * MX + s) * 3;
        out_grid[gb + 0] = gx;
        out_grid[gb + 1] = gy;
        out_grid[gb + 2] = gz;
    }

    // distances to all atoms + dv output
    const size_t dvb = ((size_t)n * MX + s) * (MAC * 3);
    #pragma unroll
    for (int j = 0; j < MAC; ++j) {
        float dx = gx - cs[j * 3 + 0];
        float dy = gy - cs[j * 3 + 1];
        float dz = gz - cs[j * 3 + 2];
        out_dv[dvb + j * 3 + 0] = dx;
        out_dv[dvb + j * 3 + 1] = dy;
        out_dv[dvb + j * 3 + 2] = dz;
        rxs[tid][j] = sqrtf(dx * dx + dy * dy + dz * dz);
    }

    // Becke cell functions: cell[i] = prod_j s(mu_ij), v = cell[a]/sum(cell)
    float cell_sum = 0.0f, cell_a = 0.0f;
    for (int i = 0; i < MAC; ++i) {
        const float rxi = rxs[tid][i];
        float p = 1.0f;
        #pragma unroll
        for (int j = 0; j < MAC; ++j) {
            float mu = (rxi - rxs[tid][j]) * inv_dm[i][j];
            mu = 0.5f * mu * (3.0f - mu * mu);   // softening pass 1
            mu = 0.5f * mu * (3.0f - mu * mu);   // softening pass 2
            float sij = 0.5f * (1.0f - mu);
            p *= (i == j) ? 1.0f : sij;          // diagonal is exactly 1
        }
        cell_sum += p;
        if (i == a) cell_a = p;
    }

    const float v = cell_a / cell_sum;
    out_w[(size_t)n * MX + s] = v * sws[d] * ww[k];
}

extern "C" void kernel_launch(void* const* d_in, const int* in_sizes, int n_in,
                              void* d_out, int out_size, void* d_ws, size_t ws_size,
                              hipStream_t stream) {
    // inputs: [0]=labels (int32, unused: all >=0 -> full padding)
    //         [1]=coords f32 [N,24,3], [2]=sphere f32 [26,3], [3]=sphere_weights f32 [26]
    const float* coords = (const float*)d_in[1];
    const float* sphere = (const float*)d_in[2];
    const float* sw     = (const float*)d_in[3];

    const int nmol = in_sizes[1] / (MAC * 3);   // 8

    float* o    = (float*)d_out;
    float* ogrid = o;                                        // [N, MX, 3]
    float* odv   = ogrid + (size_t)nmol * MX * 3;            // [N, MX, MAC, 3]
    float* ow    = odv + (size_t)nmol * MX * MAC * 3;        // [N, MX]

    becke_grid_kernel<<<dim3(nmol * NCHUNK), dim3(256), 0, stream>>>(
        coords, sphere, sw, ogrid, odv, ow);
}

// Round 2
// 86.255 us; speedup vs baseline: 1.0729x; 1.0729x over previous
//
#include <hip/hip_runtime.h>
#include <math.h>

// Problem constants (reference: N=8, MA=24, DESIGN=26, RADIAL=15, SOFTENING=3, RM=5.0)
constexpr int MAC = 24;            // atoms per molecule
constexpr int DES = 26;            // sphere design points
constexpr int RAD = 15;            // radial points
constexpr int MS  = RAD * DES;     // 390 samples per atom
constexpr int MX  = MAC * MS;      // 9360 grid points per molecule
constexpr int PTS = 16;            // grid points per block
constexpr int BTH = PTS * MAC;     // 384 threads = 6 waves
constexpr int BPM = MX / PTS;      // 585 blocks per molecule (exact)

__global__ __launch_bounds__(BTH) void becke_kernel(
    const float* __restrict__ coords,   // [N, MAC, 3]
    const float* __restrict__ sphere,   // [DES, 3]
    const float* __restrict__ sw,       // [DES]
    float* __restrict__ out_grid,       // [N, MX, 3]
    float* __restrict__ out_dv,         // [N, MX, MAC, 3]
    float* __restrict__ out_w)          // [N, MX]
{
    __shared__ float cs[MAC * 3];
    __shared__ float inv_dm[MAC][MAC + 1];   // stride 25 -> 24 distinct banks, conflict-free
    __shared__ float sph[DES * 3];
    __shared__ float sws[DES];
    __shared__ float rr[RAD];
    __shared__ float ww[RAD];
    __shared__ float rxs[PTS][MAC];
    __shared__ float cell[PTS][MAC];

    const int tid = threadIdx.x;
    const int n   = blockIdx.x / BPM;
    const int s0  = (blockIdx.x - n * BPM) * PTS;

    // ---- stage molecule coords + quadrature tables ----
    if (tid < MAC * 3) cs[tid] = coords[n * MAC * 3 + tid];
    if (tid >= 128 && tid < 128 + DES * 3) sph[tid - 128] = sphere[tid - 128];
    if (tid >= 224 && tid < 224 + DES) sws[tid - 224] = sw[tid - 224];
    if (tid >= 256 && tid < 256 + RAD) {
        double i   = (double)(tid - 256) + 1.0;
        double z   = -cos(M_PI * (2.0 * i - 1.0) / (2.0 * (double)RAD));
        double omz = 1.0 - z;
        double dr  = 2.0 * 5.0 / (omz * omz);       // RM = 5.0
        double rq  = 5.0 * (1.0 + z) / omz;
        double w1  = sqrt(1.0 - z * z) * dr * M_PI / (double)RAD;
        rr[tid - 256] = (float)rq;
        ww[tid - 256] = (float)(rq * rq * 4.0 * M_PI * w1);
    }
    __syncthreads();

    // ---- inv pairwise distances (needs cs) ----
    for (int e = tid; e < MAC * MAC; e += BTH) {
        int ii = e / MAC, jj = e - ii * MAC;
        float dx = cs[ii * 3 + 0] - cs[jj * 3 + 0];
        float dy = cs[ii * 3 + 1] - cs[jj * 3 + 1];
        float dz = cs[ii * 3 + 2] - cs[jj * 3 + 2];
        float dd = sqrtf(dx * dx + dy * dy + dz * dz);
        inv_dm[ii][jj] = 1.0f / fmaxf(dd, 1e-12f);
    }

    // ---- per-(point, atom) geometry: thread (p, i) ----
    const int p = tid / MAC;
    const int i = tid - p * MAC;
    const int s = s0 + p;                 // grid point index in molecule
    const int a = s / MS;                 // parent atom
    const int t = s - a * MS;
    const int k = t / DES;                // radial index
    const int d = t - k * DES;            // design index

    const float rq = rr[k];
    const float gx = cs[a * 3 + 0] + rq * sph[d * 3 + 0];
    const float gy = cs[a * 3 + 1] + rq * sph[d * 3 + 1];
    const float gz = cs[a * 3 + 2] + rq * sph[d * 3 + 2];

    if (i == 0) {
        size_t gb = ((size_t)n * MX + s) * 3;
        out_grid[gb + 0] = gx;
        out_grid[gb + 1] = gy;
        out_grid[gb + 2] = gz;
    }

    // dv[n, s, i, :] and rx[s][i] — each (p,i) thread one atom
    const float dx = gx - cs[i * 3 + 0];
    const float dy = gy - cs[i * 3 + 1];
    const float dz = gz - cs[i * 3 + 2];
    {
        size_t dvb = (((size_t)n * MX + s) * MAC + i) * 3;
        out_dv[dvb + 0] = dx;
        out_dv[dvb + 1] = dy;
        out_dv[dvb + 2] = dz;
    }
    const float rxi = sqrtf(dx * dx + dy * dy + dz * dz);
    rxs[p][i] = rxi;
    __syncthreads();   // covers rxs stores AND inv_dm staging

    // copy this point's rx row to registers (static indexing, no LDS in hot loop reads except inv_dm)
    float rxl[MAC];
    #pragma unroll
    for (int j = 0; j < MAC; ++j) rxl[j] = rxs[p][j];

    float prod = 1.0f;
    #pragma unroll
    for (int j = 0; j < MAC; ++j) {
        float mu = (rxi - rxl[j]) * inv_dm[i][j];
        mu = 0.5f * mu * (3.0f - mu * mu);   // softening pass 1
        mu = 0.5f * mu * (3.0f - mu * mu);   // softening pass 2
        float sij = 0.5f * (1.0f - mu);
        prod *= (j == i) ? 1.0f : sij;       // diagonal term is exactly 1
    }
    cell[p][i] = prod;
    __syncthreads();

    // reduce the 24 cell values per point; 16 threads do it
    if (tid < PTS) {
        const int pp = tid;
        const int ss = s0 + pp;
        const int aa = ss / MS;
        const int tt = ss - aa * MS;
        const int kk = tt / DES;
        const int dd = tt - kk * DES;
        float sum = 0.0f;
        #pragma unroll
        for (int j = 0; j < MAC; ++j) sum += cell[pp][j];
        const float v = cell[pp][aa] / sum;
        out_w[(size_t)n * MX + ss] = v * sws[dd] * ww[kk];
    }
}

extern "C" void kernel_launch(void* const* d_in, const int* in_sizes, int n_in,
                              void* d_out, int out_size, void* d_ws, size_t ws_size,
                              hipStream_t stream) {
    // inputs: [0]=labels (int32, unused: all >=0 -> full padding)
    //         [1]=coords f32 [N,24,3], [2]=sphere f32 [26,3], [3]=sphere_weights f32 [26]
    const float* coords = (const float*)d_in[1];
    const float* sphere = (const float*)d_in[2];
    const float* sw     = (const float*)d_in[3];

    const int nmol = in_sizes[1] / (MAC * 3);   // 8

    float* o     = (float*)d_out;
    float* ogrid = o;                                        // [N, MX, 3]
    float* odv   = ogrid + (size_t)nmol * MX * 3;            // [N, MX, MAC, 3]
    float* ow    = odv + (size_t)nmol * MX * MAC * 3;        // [N, MX]

    becke_kernel<<<dim3(nmol * BPM), dim3(BTH), 0, stream>>>(
        coords, sphere, sw, ogrid, odv, ow);
}

// Round 3
// 84.060 us; speedup vs baseline: 1.1010x; 1.0261x over previous
//
#include <hip/hip_runtime.h>
#include <math.h>

// Problem constants (reference: N=8, MA=24, DESIGN=26, RADIAL=15, SOFTENING=3, RM=5.0)
constexpr int MAC = 24;            // atoms per molecule
constexpr int DES = 26;            // sphere design points
constexpr int RAD = 15;            // radial points
constexpr int MS  = RAD * DES;     // 390 samples per atom
constexpr int MX  = MAC * MS;      // 9360 grid points per molecule
constexpr int PPB = 8;             // points per block (256 threads / 32 lanes-per-point)
constexpr int BPM = MX / PPB;      // 1170 blocks per molecule (exact)

// ---------------------------------------------------------------------------
// Kernel 1: one small block precomputes all shared tables into d_ws.
//   inv_dm [nmol][24][24] : 1/clip(|ci-cj|, 1e-12)
//   conc4  [390][4]       : r_k * sphere_d (xyz + pad, float4-loadable)
//   wt     [390]          : sphere_weights[d] * radial_w[k]
// ---------------------------------------------------------------------------
__global__ __launch_bounds__(512) void becke_precompute(
    const float* __restrict__ coords, const float* __restrict__ sphere,
    const float* __restrict__ sw, int nmol,
    float* __restrict__ inv_dm, float* __restrict__ conc4, float* __restrict__ wt)
{
    __shared__ float rr[RAD], ww[RAD];
    const int tid = threadIdx.x;
    if (tid < RAD) {
        // Gauss-Chebyshev + Becke transform radial quadrature (f64 once, here only)
        double i   = (double)tid + 1.0;
        double z   = -cos(M_PI * (2.0 * i - 1.0) / (2.0 * (double)RAD));
        double omz = 1.0 - z;
        double dr  = 10.0 / (omz * omz);            // 2*RM, RM = 5.0
        double r   = 5.0 * (1.0 + z) / omz;
        double w1  = sqrt(1.0 - z * z) * dr * M_PI / (double)RAD;
        rr[tid] = (float)r;
        ww[tid] = (float)(r * r * 4.0 * M_PI * w1);
    }
    __syncthreads();
    for (int t = tid; t < MS; t += 512) {
        int k = t / DES, d = t - k * DES;
        conc4[t * 4 + 0] = rr[k] * sphere[d * 3 + 0];
        conc4[t * 4 + 1] = rr[k] * sphere[d * 3 + 1];
        conc4[t * 4 + 2] = rr[k] * sphere[d * 3 + 2];
        conc4[t * 4 + 3] = 0.0f;
        wt[t] = sw[d] * ww[k];
    }
    for (int e = tid; e < nmol * MAC * MAC; e += 512) {
        int n = e / (MAC * MAC), r0 = e - n * MAC * MAC;
        int i = r0 / MAC, j = r0 - i * MAC;
        const float* cb = coords + n * MAC * 3;
        float dx = cb[i * 3 + 0] - cb[j * 3 + 0];
        float dy = cb[i * 3 + 1] - cb[j * 3 + 1];
        float dz = cb[i * 3 + 2] - cb[j * 3 + 2];
        float dd = sqrtf(dx * dx + dy * dy + dz * dz);
        inv_dm[e] = 1.0f / fmaxf(dd, 1e-12f);
    }
}

// ---------------------------------------------------------------------------
// Kernel 2: hot kernel. 32 lanes per grid point (lanes 0..23 = atom rows,
// lanes 24..31 pad). No __syncthreads, no LDS arrays — cross-lane data via
// __shfl (ds_bpermute, co-issues on the LDS pipe).
// ---------------------------------------------------------------------------
__global__ __launch_bounds__(256) void becke_main(
    const float* __restrict__ coords,   // [nmol, 24, 3]
    const float* __restrict__ inv_dm,   // [nmol, 24, 24]
    const float* __restrict__ conc4,    // [390, 4]
    const float* __restrict__ wt,       // [390]
    float* __restrict__ og,             // [nmol, MX, 3]
    float* __restrict__ odv,            // [nmol, MX, 24, 3]
    float* __restrict__ ow)             // [nmol, MX]
{
    const int tid = threadIdx.x;
    const int l   = tid & 31;                          // lane within point-group
    const int n   = blockIdx.x / BPM;                  // molecule (block-uniform)
    const int sm  = (blockIdx.x - n * BPM) * PPB + (tid >> 5);  // point in molecule
    const int a   = sm / MS;                           // parent atom
    const int t   = sm - a * MS;                       // sample index (radial*design)
    const bool act = (l < MAC);
    const int  i   = act ? l : (MAC - 1);              // clamp pad lanes in-bounds

    const float4 cc  = *reinterpret_cast<const float4*>(conc4 + t * 4); // broadcast
    const float  wtt = wt[t];                                           // broadcast
    const float* cb  = coords + n * MAC * 3;

    const float gx = cb[a * 3 + 0] + cc.x;
    const float gy = cb[a * 3 + 1] + cc.y;
    const float gz = cb[a * 3 + 2] + cc.z;

    const float dx = gx - cb[i * 3 + 0];
    const float dy = gy - cb[i * 3 + 1];
    const float dz = gz - cb[i * 3 + 2];
    const size_t sg = (size_t)n * MX + sm;
    if (act) {
        float* dvp = odv + (sg * MAC + i) * 3;
        dvp[0] = dx; dvp[1] = dy; dvp[2] = dz;
    }
    const float rxi = sqrtf(dx * dx + dy * dy + dz * dz);

    // this lane's inv_dm row (16B-aligned: row stride 96B)
    float inv[MAC];
    const float* irow = inv_dm + (n * MAC + i) * MAC;
    #pragma unroll
    for (int q = 0; q < MAC / 4; ++q) {
        float4 v = *reinterpret_cast<const float4*>(irow + q * 4);
        inv[q * 4 + 0] = v.x; inv[q * 4 + 1] = v.y;
        inv[q * 4 + 2] = v.z; inv[q * 4 + 3] = v.w;
    }

    // Becke row product over all j INCLUDING the diagonal:
    // s(mu_ii)=s(0)=0.5 exactly, undone by the *2 below (exact).
    float prod = 1.0f;
    #pragma unroll
    for (int j = 0; j < MAC; ++j) {
        float rxj = __shfl(rxi, j, 32);
        float mu  = (rxi - rxj) * inv[j];
        mu *= fmaf(mu * mu, -0.5f, 1.5f);   // softening pass 1: 0.5*mu*(3-mu^2)
        mu *= fmaf(mu * mu, -0.5f, 1.5f);   // softening pass 2
        prod *= fmaf(mu, -0.5f, 0.5f);      // s = 0.5*(1-mu)
    }
    float cell = act ? (prod + prod) : 0.0f;

    float sum = cell;
    #pragma unroll
    for (int m = 16; m >= 1; m >>= 1) sum += __shfl_xor(sum, m, 32);
    const float ca = __shfl(cell, a, 32);

    if (l == MAC) {             // pad lane 24: grid point
        float* gp = og + sg * 3;
        gp[0] = gx; gp[1] = gy; gp[2] = gz;
    } else if (l == MAC + 1) {  // pad lane 25: weight
        ow[sg] = (ca / sum) * wtt;
    }
}

extern "C" void kernel_launch(void* const* d_in, const int* in_sizes, int n_in,
                              void* d_out, int out_size, void* d_ws, size_t ws_size,
                              hipStream_t stream) {
    // inputs: [0]=labels (int32, unused: all >=0 -> full padding)
    //         [1]=coords f32 [N,24,3], [2]=sphere f32 [26,3], [3]=sphere_weights f32 [26]
    const float* coords = (const float*)d_in[1];
    const float* sphere = (const float*)d_in[2];
    const float* sw     = (const float*)d_in[3];

    const int nmol = in_sizes[1] / (MAC * 3);   // 8

    float* ws     = (float*)d_ws;
    float* inv_dm = ws;                           // nmol*576 floats
    float* conc4  = inv_dm + (size_t)nmol * MAC * MAC;  // 390*4 (16B-aligned: nmol*2304B)
    float* wtab   = conc4 + MS * 4;               // 390

    float* o     = (float*)d_out;
    float* ogrid = o;                                        // [N, MX, 3]
    float* odv   = ogrid + (size_t)nmol * MX * 3;            // [N, MX, MAC, 3]
    float* owt   = odv + (size_t)nmol * MX * MAC * 3;        // [N, MX]

    becke_precompute<<<dim3(1), dim3(512), 0, stream>>>(
        coords, sphere, sw, nmol, inv_dm, conc4, wtab);
    becke_main<<<dim3(nmol * BPM), dim3(256), 0, stream>>>(
        coords, inv_dm, conc4, wtab, ogrid, odv, owt);
}